// Round 9
// baseline (91.278 us; speedup 1.0000x reference)
//
#include <hip/hip_runtime.h>
#include <math.h>

#define BB 8
#define SS 4096
#define DD 1024
#define HH 16

typedef __attribute__((ext_vector_type(4))) float f32x4;
typedef __fp16 fp16x2 __attribute__((ext_vector_type(2)));
typedef _Float16 half8v __attribute__((ext_vector_type(8)));

// ws layout (no aliasing):
//   plog    [2][BB][SS][HH] fp32 = 4 MB   @ 0      (K-half partial logits)
//   partial [16][BB][HH][DD]fp32 = 8 MB   @ 6 MB
//   wh16/wl16 fp16 frag streams 32+32 KB  @ 22 MB
//   bred    [BB][32][HH] float2  = 32 KB  @ 23 MB  (per-chunk softmax partials)

// online-softmax merge: (m,z) <- (m,z) ⊕ (om,oz)
__device__ __forceinline__ void sm_merge(float& m, float& z, float om, float oz) {
  float nm = fmaxf(m, om);
  if (nm > -INFINITY)
    z = z * __expf(m - nm) + oz * __expf(om - nm);
  m = nm;
}

// K0: W fp16 hi/lo frag streams. Element e of lane l at K-step t <-> k =
// t*32 + (l>>4)*8 + e, col h = l&15. Layout [t][lane][e], t = 0..31.
__global__ __launch_bounds__(256) void k_prepw(
    const float* __restrict__ W, ushort* __restrict__ wh16, ushort* __restrict__ wl16) {
  int i = blockIdx.x * 256 + threadIdx.x;  // 16384
  int t = i >> 9;
  int l = (i >> 3) & 63;
  int e = i & 7;
  int d = t * 32 + (l >> 4) * 8 + e;
  int h = l & 15;
  float w = W[d * HH + h];
  _Float16 wh = (_Float16)w;               // RNE
  _Float16 wl = (_Float16)(w - (float)wh); // residual, |wl| <= 2^-11 |w|
  union { _Float16 f; ushort u; } ch, cl;
  ch.f = wh; cl.f = wl;
  wh16[i] = ch.u;
  wl16[i] = cl.u;
}

// DMA one 4 KB chunk (16 rows x 16 units) into a wave's LDS buf: 4 x 16B/lane.
// LDS dest is LINEAR (lane x 16B); the swizzle lives in the per-lane global
// source (gsrc) and the read side, using the same XOR involution (rule #21).
__device__ __forceinline__ void stage_chunk(const float* const* gsrc, char* lb, int c) {
#pragma unroll
  for (int k = 0; k < 4; ++k)
    __builtin_amdgcn_global_load_lds(
        (const __attribute__((address_space(1))) void*)(gsrc[k] + c * 64),
        (__attribute__((address_space(3))) void*)(lb + k * 1024), 16, 0, 0);
}

// K1 v5: DMA-staged fp16-split MFMA logits with hand-counted vmcnt pipeline.
// Wave-private LDS double buffer -> NO barriers. Steady state keeps
// G(c+1)+W(c+1) = 8 VMEM in flight across every wait (vmcnt(8), never 0).
// grid 1024 (= 512 s-tiles x 2 k-halves), block 256 = 4 independent waves.
__global__ __launch_bounds__(256, 4) void k_logits(
    const float* __restrict__ x, const ushort* __restrict__ wh16,
    const ushort* __restrict__ wl16, float* __restrict__ plog) {
  __shared__ float4 lds4[2][4][16][16];  // [buf][wave][row][unit], 32 KB

  const int tid = threadIdx.x;
  const int lane = tid & 63;
  const int wv = __builtin_amdgcn_readfirstlane(tid >> 6);
  const int kh = blockIdx.x & 1;
  const int tile = blockIdx.x >> 1;
  const int b = tile >> 6;
  const int s0 = (tile & 63) * 64;
  const int r15 = lane & 15;      // A row within wave tile / D col
  const int kg = lane >> 4;       // k-group

  const float* xw = x + ((size_t)b * SS + s0 + wv * 16) * DD + kh * 512;
  // Offset by K-half; indexed with LOCAL t (= 2c+t4) below.
  const half8v* bhp = reinterpret_cast<const half8v*>(wh16) + (kh * 16 * 64 + lane);
  const half8v* blp = reinterpret_cast<const half8v*>(wl16) + (kh * 16 * 64 + lane);

  // Per-lane pre-swizzled global bases: load k, lane l covers LDS slot
  // row = k*4 + (l>>4), unit' = l&15; data there must be (row, u=unit'^(row&7)).
  const float* gsrc[4];
#pragma unroll
  for (int k = 0; k < 4; ++k) {
    int row = k * 4 + (lane >> 4);
    int u = (lane & 15) ^ (row & 7);
    gsrc[k] = xw + (size_t)row * DD + u * 4;
  }

  f32x4 acch = {0.f, 0.f, 0.f, 0.f};
  f32x4 accl = {0.f, 0.f, 0.f, 0.f};
  half8v whf[2][2], wlf[2][2];

  char* lb0 = (char*)&lds4[0][wv][0][0];
  char* lb1 = (char*)&lds4[1][wv][0][0];

  // prologue: G(0), W(0), G(1), W(1)  -> 16 VMEM outstanding
  stage_chunk(gsrc, lb0, 0);
  whf[0][0] = bhp[0 * 64]; whf[0][1] = bhp[1 * 64];
  wlf[0][0] = blp[0 * 64]; wlf[0][1] = blp[1 * 64];
  stage_chunk(gsrc, lb1, 1);
  whf[1][0] = bhp[2 * 64]; whf[1][1] = bhp[3 * 64];
  wlf[1][0] = blp[2 * 64]; wlf[1][1] = blp[3 * 64];

#pragma unroll
  for (int c = 0; c < 8; ++c) {
    // wait G(c)+W(c) done; keep G(c+1)+W(c+1) (8 ops) in flight. Last iter: drain.
    if (c < 7) asm volatile("s_waitcnt vmcnt(8)" ::: "memory");
    else       asm volatile("s_waitcnt vmcnt(0)" ::: "memory");

#pragma unroll
    for (int t4 = 0; t4 < 2; ++t4) {
      const int u0 = t4 * 8 + kg * 2;
      float4 va = lds4[c & 1][wv][r15][u0 ^ (r15 & 7)];
      float4 vb = lds4[c & 1][wv][r15][(u0 + 1) ^ (r15 & 7)];
      union { fp16x2 h2[4]; half8v h8; } ax;
      ax.h2[0] = __builtin_amdgcn_cvt_pkrtz(va.x, va.y);
      ax.h2[1] = __builtin_amdgcn_cvt_pkrtz(va.z, va.w);
      ax.h2[2] = __builtin_amdgcn_cvt_pkrtz(vb.x, vb.y);
      ax.h2[3] = __builtin_amdgcn_cvt_pkrtz(vb.z, vb.w);
      acch = __builtin_amdgcn_mfma_f32_16x16x32_f16(ax.h8, whf[c & 1][t4], acch, 0, 0, 0);
      accl = __builtin_amdgcn_mfma_f32_16x16x32_f16(ax.h8, wlf[c & 1][t4], accl, 0, 0, 0);
    }

    if (c < 6) {
      // ds_reads of buf[c&1] must retire before the DMA overwrites it
      asm volatile("s_waitcnt lgkmcnt(0)" ::: "memory");
      stage_chunk(gsrc, (c & 1) ? lb1 : lb0, c + 2);         // G(c+2)
      whf[c & 1][0] = bhp[(2 * (c + 2) + 0) * 64];           // W(c+2)
      whf[c & 1][1] = bhp[(2 * (c + 2) + 1) * 64];
      wlf[c & 1][0] = blp[(2 * (c + 2) + 0) * 64];
      wlf[c & 1][1] = blp[(2 * (c + 2) + 1) * 64];
    }
  }

  // D layout: col = r15, row = kg*4+q (m89-verified; passed R2/R3/R5/R7/R8)
  float* ob = plog + (size_t)kh * (BB * SS * HH) +
              ((size_t)b * SS + s0 + wv * 16) * HH;
#pragma unroll
  for (int q = 0; q < 4; ++q)
    ob[(size_t)(kg * 4 + q) * HH + r15] = acch[q] + accl[q];
}

// K2: per (b, 128-row s-chunk) online-softmax partials (m, Z) per h.
// grid 256 (= 8 b x 32 chunks), block 256. Coalesced float4 reads of plog.
__global__ __launch_bounds__(256) void k_smpart(
    const float* __restrict__ plog, const int* __restrict__ mask,
    float2* __restrict__ bred) {  // bred[BB][32][HH]
  __shared__ float4 smm[4][4], smz[4][4];
  const int tid = threadIdx.x;
  const int lane = tid & 63;
  const int wv = tid >> 6;
  const int b = blockIdx.x >> 5;
  const int sc = blockIdx.x & 31;
  const int s0 = sc * 128;
  const float4* p0 = reinterpret_cast<const float4*>(plog + ((size_t)b * SS + s0) * HH);
  const float4* p1 = reinterpret_cast<const float4*>(
      plog + (size_t)BB * SS * HH + ((size_t)b * SS + s0) * HH);
  const int* mb = mask + b * SS + s0;

  float m4[4] = {-INFINITY, -INFINITY, -INFINITY, -INFINITY};
  float z4[4] = {0.f, 0.f, 0.f, 0.f};
#pragma unroll
  for (int i = 0; i < 2; ++i) {
    int f = i * 256 + tid;
    float4 va = p0[f];
    float4 vb = p1[f];
    int msk = mb[f >> 2];
    float lv[4] = {(va.x + vb.x) * 0.125f, (va.y + vb.y) * 0.125f,
                   (va.z + vb.z) * 0.125f, (va.w + vb.w) * 0.125f};
#pragma unroll
    for (int j = 0; j < 4; ++j) {
      float v = msk ? lv[j] : -INFINITY;
      sm_merge(m4[j], z4[j], v, 1.0f);
    }
  }
#pragma unroll
  for (int off = 4; off < 64; off <<= 1) {
#pragma unroll
    for (int j = 0; j < 4; ++j) {
      float om = __shfl_xor(m4[j], off, 64);
      float oz = __shfl_xor(z4[j], off, 64);
      sm_merge(m4[j], z4[j], om, oz);
    }
  }
  if (lane < 4) {
    smm[wv][lane] = make_float4(m4[0], m4[1], m4[2], m4[3]);
    smz[wv][lane] = make_float4(z4[0], z4[1], z4[2], z4[3]);
  }
  __syncthreads();
  if (tid < 4) {
    float4 mm = smm[0][tid], zz = smz[0][tid];
    float fm[4] = {mm.x, mm.y, mm.z, mm.w};
    float fz[4] = {zz.x, zz.y, zz.z, zz.w};
#pragma unroll
    for (int w = 1; w < 4; ++w) {
      float4 om4 = smm[w][tid], oz4 = smz[w][tid];
      float om[4] = {om4.x, om4.y, om4.z, om4.w};
      float oz[4] = {oz4.x, oz4.y, oz4.z, oz4.w};
#pragma unroll
      for (int j = 0; j < 4; ++j) sm_merge(fm[j], fz[j], om[j], oz[j]);
    }
#pragma unroll
    for (int j = 0; j < 4; ++j)
      bred[((size_t)b * 32 + sc) * HH + tid * 4 + j] = make_float2(fm[j], fz[j]);
  }
}

// K3: pooling with inline softmax finalize. grid 256 (= 8 b x 16 sc x 2 dh),
// block 256; thread owns 2 d over 256-row s-chunks (partial traffic halved).
__global__ __launch_bounds__(256) void k_pool(
    const float* __restrict__ x, const float* __restrict__ plog,
    const float2* __restrict__ bred, const int* __restrict__ mask,
    float* __restrict__ partial) {
  __shared__ float wl[256][16];  // 16 KB
  __shared__ float fm[16], fz[16];
  const int tid = threadIdx.x;
  const int dh = blockIdx.x & 1;
  const int sc = (blockIdx.x >> 1) & 15;
  const int b = blockIdx.x >> 5;
  const int s0 = sc * 256;

  if (tid < 16) {
    float m = -INFINITY, z = 0.f;
#pragma unroll 4
    for (int c = 0; c < 32; ++c) {
      float2 p = bred[((size_t)b * 32 + c) * HH + tid];
      sm_merge(m, z, p.x, p.y);
    }
    fm[tid] = m;
    fz[tid] = (z > 0.f) ? 1.0f / z : 0.f;
  }
  __syncthreads();

  const float4* p0 = reinterpret_cast<const float4*>(plog + ((size_t)b * SS + s0) * HH);
  const float4* p1 = reinterpret_cast<const float4*>(
      plog + (size_t)BB * SS * HH + ((size_t)b * SS + s0) * HH);
  const int* mb = mask + b * SS + s0;
#pragma unroll
  for (int k = 0; k < 4; ++k) {
    int f = k * 256 + tid;  // float4 over [256][16]
    float4 va = p0[f];
    float4 vb = p1[f];
    int msk = mb[f >> 2];
    int hb = (f & 3) * 4;
    float4 w;
    w.x = msk ? __expf((va.x + vb.x) * 0.125f - fm[hb + 0]) * fz[hb + 0] : 0.f;
    w.y = msk ? __expf((va.y + vb.y) * 0.125f - fm[hb + 1]) * fz[hb + 1] : 0.f;
    w.z = msk ? __expf((va.z + vb.z) * 0.125f - fm[hb + 2]) * fz[hb + 2] : 0.f;
    w.w = msk ? __expf((va.w + vb.w) * 0.125f - fm[hb + 3]) * fz[hb + 3] : 0.f;
    *reinterpret_cast<float4*>(&wl[0][0] + f * 4) = w;
  }
  __syncthreads();

  float2 acc[HH];
#pragma unroll
  for (int h = 0; h < HH; ++h) acc[h] = make_float2(0.f, 0.f);

  const float* xb = x + ((size_t)b * SS + s0) * DD + dh * 512 + tid * 2;
#pragma unroll 8
  for (int s = 0; s < 256; ++s) {
    float2 xv = *reinterpret_cast<const float2*>(xb + (size_t)s * DD);
    const float4* wrow = reinterpret_cast<const float4*>(wl[s]);
    float4 wa = wrow[0], wb_ = wrow[1], wc = wrow[2], wd = wrow[3];
    float wvv[16] = {wa.x, wa.y, wa.z, wa.w, wb_.x, wb_.y, wb_.z, wb_.w,
                     wc.x, wc.y, wc.z, wc.w, wd.x, wd.y, wd.z, wd.w};
#pragma unroll
    for (int h = 0; h < HH; ++h) {
      float w = wvv[h];
      acc[h].x += w * xv.x;
      acc[h].y += w * xv.y;
    }
  }

  float* pb = partial + ((size_t)sc * BB + b) * (HH * DD) + dh * 512 + tid * 2;
#pragma unroll
  for (int h = 0; h < HH; ++h)
    *reinterpret_cast<float2*>(pb + (size_t)h * DD) = acc[h];
}

// K4: reduce 16 s-chunk partials. grid 512, block 256.
__global__ __launch_bounds__(256) void k_reduce(
    const float* __restrict__ partial, float* __restrict__ out) {
  const int idx = blockIdx.x * 256 + threadIdx.x;
  float s = 0.f;
#pragma unroll
  for (int c = 0; c < 16; ++c) s += partial[(size_t)c * (BB * HH * DD) + idx];
  out[idx] = s;
}

extern "C" void kernel_launch(void* const* d_in, const int* in_sizes, int n_in,
                              void* d_out, int out_size, void* d_ws, size_t ws_size,
                              hipStream_t stream) {
  const float* x = (const float*)d_in[0];     // [8][4096][1024] fp32
  const float* W = (const float*)d_in[1];     // [1024][16] fp32
  const int* mask = (const int*)d_in[2];      // [8][4096] int32
  float* out = (float*)d_out;                 // [8][16384] fp32

  char* ws = (char*)d_ws;
  float* plog    = (float*)ws;                                   // 4 MB
  float* partial = (float*)(ws + (size_t)6 * 1024 * 1024);       // 8 MB
  ushort* wh16   = (ushort*)(ws + (size_t)22 * 1024 * 1024);     // 32 KB
  ushort* wl16   = (ushort*)(ws + (size_t)22 * 1024 * 1024 + 32 * 1024);
  float2* bred   = (float2*)(ws + (size_t)23 * 1024 * 1024);     // 32 KB

  k_prepw<<<64, 256, 0, stream>>>(W, wh16, wl16);
  k_logits<<<1024, 256, 0, stream>>>(x, wh16, wl16, plog);
  k_smpart<<<256, 256, 0, stream>>>(plog, mask, bred);
  k_pool<<<256, 256, 0, stream>>>(x, plog, bred, mask, partial);
  k_reduce<<<512, 256, 0, stream>>>(partial, out);
}

// Round 10
// 70.986 us; speedup vs baseline: 1.2859x; 1.2859x over previous
//
#include <hip/hip_runtime.h>
#include <math.h>

#define BB 8
#define SS 4096
#define DD 1024
#define HH 16

typedef __attribute__((ext_vector_type(4))) float f32x4;
typedef __fp16 fp16x2 __attribute__((ext_vector_type(2)));
typedef _Float16 half8v __attribute__((ext_vector_type(8)));

// ws layout (no aliasing):
//   plog    [BB][SS][HH] fp32 = 2 MB   @ 0      (scaled+masked logits)
//   partial [32][BB][HH][DD]  = 16 MB  @ 6 MB
//   wh16/wl16 fp16 frag streams 32+32 KB @ 22 MB
//   bred    [BB][64][HH] float2 = 64 KB @ 23 MB (per-64-row-chunk softmax partials)

// online-softmax merge: (m,z) <- (m,z) ⊕ (om,oz)
__device__ __forceinline__ void sm_merge(float& m, float& z, float om, float oz) {
  float nm = fmaxf(m, om);
  if (nm > -INFINITY)
    z = z * __expf(m - nm) + oz * __expf(om - nm);
  m = nm;
}

// K0: W fp16 hi/lo frag streams. Element e of lane l at K-step t <-> k =
// t*32 + (l>>4)*8 + e, col h = l&15. Layout [t][lane][e], t = 0..31.
__global__ __launch_bounds__(256) void k_prepw(
    const float* __restrict__ W, ushort* __restrict__ wh16, ushort* __restrict__ wl16) {
  int i = blockIdx.x * 256 + threadIdx.x;  // 16384
  int t = i >> 9;
  int l = (i >> 3) & 63;
  int e = i & 7;
  int d = t * 32 + (l >> 4) * 8 + e;
  int h = l & 15;
  float w = W[d * HH + h];
  _Float16 wh = (_Float16)w;               // RNE
  _Float16 wl = (_Float16)(w - (float)wh); // residual
  union { _Float16 f; ushort u; } ch, cl;
  ch.f = wh; cl.f = wl;
  wh16[i] = ch.u;
  wl16[i] = cl.u;
}

// K1 v6: full-K fp16-split MFMA logits + fused chunk-softmax partials.
// R8's reg-staged wave-private pipeline (the proven one), deepened to 3 chunks.
// grid 512 (= 8 b x 64 s-tiles of 64 rows), block 256 = 4 independent waves.
#define XLOAD(dst, c)                                                          \
  _Pragma("unroll") for (int k = 0; k < 4; ++k) {                              \
    int row = k * 4 + srow;                                                    \
    dst[k] = *reinterpret_cast<const float4*>(                                 \
        xw + (size_t)row * DD + (c) * 64 + sul * 4);                           \
  }
#define XSTAGE(src, c)                                                         \
  _Pragma("unroll") for (int k = 0; k < 4; ++k) {                              \
    int row = k * 4 + srow;                                                    \
    lds4[(c) & 1][wv][row][sul ^ (row & 7)] = src[k];                          \
  }
#define WLOAD(c)                                                               \
  whf[(c) & 1][0] = bhp[(2 * (c) + 0) * 64];                                   \
  whf[(c) & 1][1] = bhp[(2 * (c) + 1) * 64];                                   \
  wlf[(c) & 1][0] = blp[(2 * (c) + 0) * 64];                                   \
  wlf[(c) & 1][1] = blp[(2 * (c) + 1) * 64];

__global__ __launch_bounds__(256, 2) void k_logits(
    const float* __restrict__ x, const ushort* __restrict__ wh16,
    const ushort* __restrict__ wl16, const int* __restrict__ mask,
    float* __restrict__ plog, float2* __restrict__ bred) {
  __shared__ float4 lds4[2][4][16][16];  // [buf][wave][row][unit], 32 KB
  __shared__ float2 smch[4][16];

  const int tid = threadIdx.x;
  const int lane = tid & 63;
  const int wv = __builtin_amdgcn_readfirstlane(tid >> 6);
  const int b = blockIdx.x >> 6;
  const int tile = blockIdx.x & 63;
  const int s0 = tile * 64;
  const int r15 = lane & 15;      // A row within wave tile / D col (h)
  const int kg = lane >> 4;       // k-group
  const int srow = lane >> 4;     // staging sub-row
  const int sul = lane & 15;      // staging unit (16 B)

  const float* xw = x + ((size_t)b * SS + s0 + wv * 16) * DD;
  const half8v* bhp = reinterpret_cast<const half8v*>(wh16) + lane;
  const half8v* blp = reinterpret_cast<const half8v*>(wl16) + lane;

  f32x4 acch = {0.f, 0.f, 0.f, 0.f};
  f32x4 accl = {0.f, 0.f, 0.f, 0.f};
  float4 st[3][4];
  half8v whf[2][2], wlf[2][2];

  // prologue: 3-deep x prefetch; stage chunk 0; W chunks 0,1
  XLOAD(st[0], 0);
  XLOAD(st[1], 1);
  XLOAD(st[2], 2);
  XSTAGE(st[0], 0);
  WLOAD(0);
  WLOAD(1);

#pragma unroll
  for (int c = 0; c < 16; ++c) {
    if (c < 13) { XLOAD(st[(c + 3) % 3], c + 3); }  // buf (c%3) held chunk c: staged already

#pragma unroll
    for (int t4 = 0; t4 < 2; ++t4) {
      const int u0 = t4 * 8 + kg * 2;
      float4 va = lds4[c & 1][wv][r15][u0 ^ (r15 & 7)];
      float4 vb = lds4[c & 1][wv][r15][(u0 + 1) ^ (r15 & 7)];
      union { fp16x2 h2[4]; half8v h8; } ax;
      ax.h2[0] = __builtin_amdgcn_cvt_pkrtz(va.x, va.y);
      ax.h2[1] = __builtin_amdgcn_cvt_pkrtz(va.z, va.w);
      ax.h2[2] = __builtin_amdgcn_cvt_pkrtz(vb.x, vb.y);
      ax.h2[3] = __builtin_amdgcn_cvt_pkrtz(vb.z, vb.w);
      acch = __builtin_amdgcn_mfma_f32_16x16x32_f16(ax.h8, whf[c & 1][t4], acch, 0, 0, 0);
      accl = __builtin_amdgcn_mfma_f32_16x16x32_f16(ax.h8, wlf[c & 1][t4], accl, 0, 0, 0);
    }

    if (c < 14) { WLOAD(c + 2); }                  // whf[c&1] just consumed
    if (c < 15) { XSTAGE(st[(c + 1) % 3], c + 1); }
  }

  // epilogue: masked scaled logits -> plog; chunk (m,Z) partials -> bred.
  // D layout: col = r15 (h), row = kg*4+q (m89-verified; passed R2..R8).
  float lv[4];
  float* ob = plog + ((size_t)b * SS + s0 + wv * 16) * HH;
#pragma unroll
  for (int q = 0; q < 4; ++q) {
    int srw = kg * 4 + q;
    int msk = mask[b * SS + s0 + wv * 16 + srw];
    float v = (acch[q] + accl[q]) * 0.125f;
    lv[q] = msk ? v : -INFINITY;
    ob[(size_t)srw * HH + r15] = lv[q];
  }
  float ml = fmaxf(fmaxf(lv[0], lv[1]), fmaxf(lv[2], lv[3]));
  float zl = 0.f;
  if (ml > -INFINITY) {
#pragma unroll
    for (int q = 0; q < 4; ++q) zl += __expf(lv[q] - ml);
  }
  // merge across the 4 k-groups (lanes sharing r15)
#pragma unroll
  for (int off = 16; off < 64; off <<= 1) {
    float om = __shfl_xor(ml, off, 64);
    float oz = __shfl_xor(zl, off, 64);
    sm_merge(ml, zl, om, oz);
  }
  if (kg == 0) smch[wv][r15] = make_float2(ml, zl);
  __syncthreads();
  if (tid < 16) {
    float2 p0 = smch[0][tid];
    float m = p0.x, z = p0.y;
#pragma unroll
    for (int w = 1; w < 4; ++w) {
      float2 pw = smch[w][tid];
      sm_merge(m, z, pw.x, pw.y);
    }
    bred[((size_t)b * 64 + tile) * HH + tid] = make_float2(m, z);
  }
}

// K3: pooling with inline softmax finalize (R8 config: grid 512 = 8b x 32sc x 2dh).
__global__ __launch_bounds__(256) void k_pool(
    const float* __restrict__ x, const float* __restrict__ plog,
    const float2* __restrict__ bred, const int* __restrict__ mask,
    float* __restrict__ partial) {
  __shared__ float wl[128][16];
  __shared__ float fm[16], fz[16];
  const int tid = threadIdx.x;
  const int dh = blockIdx.x & 1;
  const int sc = (blockIdx.x >> 1) & 31;
  const int b = blockIdx.x >> 6;
  const int s0 = sc * 128;

  if (tid < 16) {
    float m = -INFINITY, z = 0.f;
#pragma unroll 4
    for (int c = 0; c < 64; ++c) {
      float2 p = bred[((size_t)b * 64 + c) * HH + tid];
      sm_merge(m, z, p.x, p.y);
    }
    fm[tid] = m;
    fz[tid] = (z > 0.f) ? 1.0f / z : 0.f;
  }
  __syncthreads();

  const float4* p0 = reinterpret_cast<const float4*>(plog + ((size_t)b * SS + s0) * HH);
  const int* mb = mask + b * SS + s0;
#pragma unroll
  for (int k = 0; k < 2; ++k) {
    int f = k * 256 + tid;  // float4 over [128][16]
    float4 va = p0[f];
    int msk = mb[f >> 2];
    int hb = (f & 3) * 4;
    float4 w;
    w.x = msk ? __expf(va.x - fm[hb + 0]) * fz[hb + 0] : 0.f;
    w.y = msk ? __expf(va.y - fm[hb + 1]) * fz[hb + 1] : 0.f;
    w.z = msk ? __expf(va.z - fm[hb + 2]) * fz[hb + 2] : 0.f;
    w.w = msk ? __expf(va.w - fm[hb + 3]) * fz[hb + 3] : 0.f;
    *reinterpret_cast<float4*>(&wl[0][0] + f * 4) = w;
  }
  __syncthreads();

  float2 acc[HH];
#pragma unroll
  for (int h = 0; h < HH; ++h) acc[h] = make_float2(0.f, 0.f);

  const float* xb = x + ((size_t)b * SS + s0) * DD + dh * 512 + tid * 2;
  for (int s = 0; s < 128; ++s) {
    float2 xv = *reinterpret_cast<const float2*>(xb + (size_t)s * DD);
    const float4* wrow = reinterpret_cast<const float4*>(wl[s]);
    float4 wa = wrow[0], wb_ = wrow[1], wc = wrow[2], wd = wrow[3];
    float wvv[16] = {wa.x, wa.y, wa.z, wa.w, wb_.x, wb_.y, wb_.z, wb_.w,
                     wc.x, wc.y, wc.z, wc.w, wd.x, wd.y, wd.z, wd.w};
#pragma unroll
    for (int h = 0; h < HH; ++h) {
      float w = wvv[h];
      acc[h].x += w * xv.x;
      acc[h].y += w * xv.y;
    }
  }

  float* pb = partial + ((size_t)sc * BB + b) * (HH * DD) + dh * 512 + tid * 2;
#pragma unroll
  for (int h = 0; h < HH; ++h)
    *reinterpret_cast<float2*>(pb + (size_t)h * DD) = acc[h];
}

// K4: reduce 32 s-chunk partials. grid 512, block 256.
__global__ __launch_bounds__(256) void k_reduce(
    const float* __restrict__ partial, float* __restrict__ out) {
  const int idx = blockIdx.x * 256 + threadIdx.x;
  float s = 0.f;
#pragma unroll
  for (int c = 0; c < 32; ++c) s += partial[(size_t)c * (BB * HH * DD) + idx];
  out[idx] = s;
}

extern "C" void kernel_launch(void* const* d_in, const int* in_sizes, int n_in,
                              void* d_out, int out_size, void* d_ws, size_t ws_size,
                              hipStream_t stream) {
  const float* x = (const float*)d_in[0];     // [8][4096][1024] fp32
  const float* W = (const float*)d_in[1];     // [1024][16] fp32
  const int* mask = (const int*)d_in[2];      // [8][4096] int32
  float* out = (float*)d_out;                 // [8][16384] fp32

  char* ws = (char*)d_ws;
  float* plog    = (float*)ws;                                   // 2 MB
  float* partial = (float*)(ws + (size_t)6 * 1024 * 1024);       // 16 MB
  ushort* wh16   = (ushort*)(ws + (size_t)22 * 1024 * 1024);     // 32 KB
  ushort* wl16   = (ushort*)(ws + (size_t)22 * 1024 * 1024 + 32 * 1024);
  float2* bred   = (float2*)(ws + (size_t)23 * 1024 * 1024);     // 64 KB

  k_prepw<<<64, 256, 0, stream>>>(W, wh16, wl16);
  k_logits<<<512, 256, 0, stream>>>(x, wh16, wl16, mask, plog, bred);
  k_pool<<<512, 256, 0, stream>>>(x, plog, bred, mask, partial);
  k_reduce<<<512, 256, 0, stream>>>(partial, out);
}